// Round 1
// baseline (602.336 us; speedup 1.0000x reference)
//
#include <hip/hip_runtime.h>

#define NN 50000
#define NE 800000
#define IND 64
#define HID 128
#define OUTD 64

// ---------------- degree ----------------
__global__ void deg_kernel(const int* __restrict__ dst, float* __restrict__ deg) {
    int e = blockIdx.x * blockDim.x + threadIdx.x;
    if (e < NE) atomicAdd(&deg[dst[e]], 1.0f);
}

__global__ void deginv_kernel(float* __restrict__ deg) {
    int i = blockIdx.x * blockDim.x + threadIdx.x;
    if (i < NN) {
        float d = deg[i];
        deg[i] = (d > 0.f) ? (1.0f / d) : 0.f;
    }
}

// ---------------- edge scatter-aggregate (mean, deg_inv folded in) ----------------
// one wave (64 lanes) per edge; lane l handles feature dim l (dim == 64)
__global__ void agg_kernel(const int* __restrict__ src, const int* __restrict__ dst,
                           const float* __restrict__ feat, const float* __restrict__ deginv,
                           float* __restrict__ outp) {
    int tid = blockIdx.x * blockDim.x + threadIdx.x;
    int e = tid >> 6;
    int l = tid & 63;
    if (e < NE) {
        int s = src[e];
        int d = dst[e];
        float w = deginv[d];
        atomicAdd(&outp[(size_t)d * 64 + l], feat[(size_t)s * 64 + l] * w);
    }
}

// ---------------- conv1: hpre = agg@W1l + b1 + x@W1r ; BN partial stats ----------------
// 256 threads: j = tid&127 (output channel), half = tid>>7 (2 nodes per iter).
// Weight columns live in registers; node vectors broadcast from LDS.
__global__ __launch_bounds__(256) void conv1_kernel(
    const float* __restrict__ x, const float* __restrict__ agg,
    const float* __restrict__ W1l, const float* __restrict__ b1,
    const float* __restrict__ W1r,
    float* __restrict__ hpre, float* __restrict__ sums, float* __restrict__ sumsq,
    int npairs)
{
    __shared__ float aggv[2][64];
    __shared__ float xv[2][64];
    int tid = threadIdx.x;
    int j = tid & 127;
    int half = tid >> 7;
    float wl[IND], wr[IND];
#pragma unroll
    for (int k = 0; k < IND; k++) {
        wl[k] = W1l[k * HID + j];
        wr[k] = W1r[k * HID + j];
    }
    float bj = b1[j];
    float lsum = 0.f, lsq = 0.f;
    for (int p = blockIdx.x; p < npairs; p += gridDim.x) {
        int n0 = p * 2;
        __syncthreads();
        {
            int which = tid >> 6;      // 0..3
            int k = tid & 63;
            int nh = which >> 1;       // node half
            int node = n0 + nh;
            if (which & 1) xv[nh][k] = x[(size_t)node * 64 + k];
            else           aggv[nh][k] = agg[(size_t)node * 64 + k];
        }
        __syncthreads();
        float acc = bj;
#pragma unroll
        for (int k = 0; k < IND; k++) {
            acc += aggv[half][k] * wl[k] + xv[half][k] * wr[k];
        }
        hpre[(size_t)(n0 + half) * HID + j] = acc;
        lsum += acc;
        lsq += acc * acc;
    }
    atomicAdd(&sums[j], lsum);
    atomicAdd(&sumsq[j], lsq);
}

// ---------------- BN stats -> scale/shift ----------------
__global__ void bnstat_kernel(const float* __restrict__ sums, const float* __restrict__ sumsq,
                              const float* __restrict__ gamma, const float* __restrict__ beta,
                              float* __restrict__ scale, float* __restrict__ shift) {
    int c = threadIdx.x;
    if (c < HID) {
        float inv_n = 1.0f / (float)NN;
        float mu = sums[c] * inv_n;
        float var = sumsq[c] * inv_n - mu * mu;
        float s = gamma[c] * rsqrtf(var + 1e-5f);
        scale[c] = s;
        shift[c] = beta[c] - mu * s;
    }
}

// ---------------- conv2 pre: h = relu(BN(hpre)); p = h@W2l ; out_self = h@W2r + b2 ----------------
// 256 threads: j = tid&127; j<64 computes p[n][j] (W2l col), j>=64 computes self[n][j-64] (W2r col).
__global__ __launch_bounds__(256) void conv2pre_kernel(
    const float* __restrict__ hpre, const float* __restrict__ scale, const float* __restrict__ shift,
    const float* __restrict__ W2l, const float* __restrict__ b2, const float* __restrict__ W2r,
    float* __restrict__ p, float* __restrict__ outp, int npairs)
{
    __shared__ float hv[2][HID];
    int tid = threadIdx.x;
    int j = tid & 127;
    int half = tid >> 7;
    int jj = j & 63;
    const float* W = (j < 64) ? W2l : W2r;
    float w[HID];
#pragma unroll
    for (int k = 0; k < HID; k++) w[k] = W[k * OUTD + jj];
    float bj = (j >= 64) ? b2[jj] : 0.f;
    float sc = scale[j], sh = shift[j];
    for (int pr = blockIdx.x; pr < npairs; pr += gridDim.x) {
        int n0 = pr * 2;
        __syncthreads();
        {
            float v = hpre[(size_t)(n0 + half) * HID + j];
            v = v * sc + sh;
            hv[half][j] = (v > 0.f) ? v : 0.f;
        }
        __syncthreads();
        float acc = bj;
#pragma unroll
        for (int k = 0; k < HID; k++) acc += hv[half][k] * w[k];
        int n = n0 + half;
        if (j < 64) p[(size_t)n * 64 + j] = acc;
        else        outp[(size_t)n * 64 + jj] = acc;
    }
}

extern "C" void kernel_launch(void* const* d_in, const int* in_sizes, int n_in,
                              void* d_out, int out_size, void* d_ws, size_t ws_size,
                              hipStream_t stream) {
    const float* x     = (const float*)d_in[0];
    const int*   ei    = (const int*)d_in[1];
    const float* W1l   = (const float*)d_in[2];
    const float* b1    = (const float*)d_in[3];
    const float* W1r   = (const float*)d_in[4];
    const float* gamma = (const float*)d_in[5];
    const float* beta  = (const float*)d_in[6];
    const float* W2l   = (const float*)d_in[7];
    const float* b2    = (const float*)d_in[8];
    const float* W2r   = (const float*)d_in[9];
    float* out = (float*)d_out;
    float* ws  = (float*)d_ws;

    // workspace layout (floats). p aliases agg (agg dead after conv1).
    float* deg   = ws;                          // N
    float* agg   = ws + NN;                     // N*64  (later reused as p)
    float* p     = agg;                         // N*64 alias
    float* hpre  = ws + (size_t)NN * 65;        // N*128
    float* sums  = ws + (size_t)NN * 193;       // 128
    float* sumsq = sums + 128;                  // 128
    float* scale = sums + 256;                  // 128
    float* shift = sums + 384;                  // 128

    const int* srcp = ei;
    const int* dstp = ei + NE;

    // zero: deg + agg (contiguous) and BN accumulators
    hipMemsetAsync(deg, 0, sizeof(float) * (size_t)NN * 65, stream);
    hipMemsetAsync(sums, 0, sizeof(float) * 256, stream);

    deg_kernel<<<(NE + 255) / 256, 256, 0, stream>>>(dstp, deg);
    deginv_kernel<<<(NN + 255) / 256, 256, 0, stream>>>(deg);
    agg_kernel<<<(NE * 64) / 256, 256, 0, stream>>>(srcp, dstp, x, deg, agg);
    conv1_kernel<<<512, 256, 0, stream>>>(x, agg, W1l, b1, W1r, hpre, sums, sumsq, NN / 2);
    bnstat_kernel<<<1, 128, 0, stream>>>(sums, sumsq, gamma, beta, scale, shift);
    conv2pre_kernel<<<512, 256, 0, stream>>>(hpre, scale, shift, W2l, b2, W2r, p, out, NN / 2);
    agg_kernel<<<(NE * 64) / 256, 256, 0, stream>>>(srcp, dstp, p, deg, out);
}

// Round 4
// 358.101 us; speedup vs baseline: 1.6820x; 1.6820x over previous
//
#include <hip/hip_runtime.h>

#define NN 50000
#define NE 800000
#define IND 64
#define HID 128
#define OUTD 64

// ---------------- CSR build: histogram ----------------
__global__ void hist_kernel(const int* __restrict__ dst, int* __restrict__ cnt) {
    int e = blockIdx.x * blockDim.x + threadIdx.x;
    if (e < NE) atomicAdd(&cnt[dst[e]], 1);
}

// ---------------- 3-phase exclusive scan over NN counts ----------------
__global__ void scan1_kernel(const int* __restrict__ cnt, int* __restrict__ excl,
                             int* __restrict__ bsum) {
    __shared__ int tmp[256];
    int tid = threadIdx.x;
    int i = blockIdx.x * 256 + tid;
    int v = (i < NN) ? cnt[i] : 0;
    tmp[tid] = v;
    __syncthreads();
    for (int off = 1; off < 256; off <<= 1) {
        int t = (tid >= off) ? tmp[tid - off] : 0;
        __syncthreads();
        tmp[tid] += t;
        __syncthreads();
    }
    if (i < NN) excl[i] = tmp[tid] - v;   // exclusive
    if (tid == 255) bsum[blockIdx.x] = tmp[255];
}

__global__ void scan2_kernel(int* __restrict__ bsum, int* __restrict__ boff, int nb) {
    __shared__ int tmp[256];
    int tid = threadIdx.x;
    int v = (tid < nb) ? bsum[tid] : 0;
    tmp[tid] = v;
    __syncthreads();
    for (int off = 1; off < 256; off <<= 1) {
        int t = (tid >= off) ? tmp[tid - off] : 0;
        __syncthreads();
        tmp[tid] += t;
        __syncthreads();
    }
    if (tid < nb) boff[tid] = tmp[tid] - v;
}

// in-place: start = excl + boff[block]; next (cursor copy) = same
__global__ void scan3_kernel(int* __restrict__ excl, const int* __restrict__ boff,
                             int* __restrict__ next) {
    int i = blockIdx.x * 256 + threadIdx.x;
    if (i < NN) {
        int s = excl[i] + boff[blockIdx.x];
        excl[i] = s;    // becomes start[]
        next[i] = s;    // scatter cursor
    }
}

// ---------------- scatter edges into CSR order ----------------
__global__ void scatter_kernel(const int* __restrict__ src, const int* __restrict__ dst,
                               int* __restrict__ next, int* __restrict__ perm) {
    int e = blockIdx.x * blockDim.x + threadIdx.x;
    if (e < NE) {
        int pos = atomicAdd(&next[dst[e]], 1);
        perm[pos] = src[e];
    }
}

// ---------------- gather-aggregate (mean): one wave per node ----------------
// 64 lanes: 4 edge-subgroups (g=lane>>4) x 16 float4 slots (q=lane&15).
// feat row s lives at feat4[s*fstride + foff .. +16); out row n at out4[n*ostride + ooff ..).
// ACCUM=true: out += mean (out already holds the self term; wave owns its node).
template<bool ACCUM>
__global__ __launch_bounds__(256) void agg_gather_kernel(
    const float4* __restrict__ feat4, int fstride, int foff,
    const int* __restrict__ start, const int* __restrict__ perm,
    float4* __restrict__ out4, int ostride, int ooff)
{
    int wave = (blockIdx.x * blockDim.x + threadIdx.x) >> 6;
    if (wave >= NN) return;
    int lane = threadIdx.x & 63;
    int g = lane >> 4;
    int q = lane & 15;
    int rs = start[wave];
    int re = (wave == NN - 1) ? NE : start[wave + 1];
    int cnt = re - rs;
    float4 acc = {0.f, 0.f, 0.f, 0.f};
    for (int i = rs + g; i < re; i += 4) {
        int s = perm[i];
        float4 v = feat4[(size_t)s * fstride + foff + q];
        acc.x += v.x; acc.y += v.y; acc.z += v.z; acc.w += v.w;
    }
    // reduce the 4 subgroups (lane bits 4,5)
    acc.x += __shfl_xor(acc.x, 16, 64); acc.y += __shfl_xor(acc.y, 16, 64);
    acc.z += __shfl_xor(acc.z, 16, 64); acc.w += __shfl_xor(acc.w, 16, 64);
    acc.x += __shfl_xor(acc.x, 32, 64); acc.y += __shfl_xor(acc.y, 32, 64);
    acc.z += __shfl_xor(acc.z, 32, 64); acc.w += __shfl_xor(acc.w, 32, 64);
    if (g == 0) {
        float inv = (cnt > 0) ? (1.0f / (float)cnt) : 0.f;
        float4 r = {acc.x * inv, acc.y * inv, acc.z * inv, acc.w * inv};
        size_t oidx = (size_t)wave * ostride + ooff + q;
        if (ACCUM) {
            float4 o = out4[oidx];
            r.x += o.x; r.y += o.y; r.z += o.z; r.w += o.w;
        }
        out4[oidx] = r;
    }
}

// ---------------- conv1: hpre = agg@W1l + b1 + x@W1r ; BN partial stats ----------------
// agg[n] lives in hpre[n][64..128) (staged to LDS before the row is overwritten).
__global__ __launch_bounds__(256) void conv1_kernel(
    const float* __restrict__ x,
    const float* __restrict__ W1l, const float* __restrict__ b1,
    const float* __restrict__ W1r,
    float* __restrict__ hpre, float* __restrict__ sums, float* __restrict__ sumsq,
    int npairs)
{
    __shared__ float aggv[2][64];
    __shared__ float xv[2][64];
    int tid = threadIdx.x;
    int j = tid & 127;
    int half = tid >> 7;
    float wl[IND], wr[IND];
#pragma unroll
    for (int k = 0; k < IND; k++) {
        wl[k] = W1l[k * HID + j];
        wr[k] = W1r[k * HID + j];
    }
    float bj = b1[j];
    float lsum = 0.f, lsq = 0.f;
    for (int p = blockIdx.x; p < npairs; p += gridDim.x) {
        int n0 = p * 2;
        __syncthreads();
        {
            int which = tid >> 6;      // 0..3
            int k = tid & 63;
            int nh = which >> 1;       // node half
            int node = n0 + nh;
            if (which & 1) xv[nh][k] = x[(size_t)node * 64 + k];
            else           aggv[nh][k] = hpre[(size_t)node * HID + 64 + k];
        }
        __syncthreads();
        float acc = bj;
#pragma unroll
        for (int k = 0; k < IND; k++) {
            acc += aggv[half][k] * wl[k] + xv[half][k] * wr[k];
        }
        hpre[(size_t)(n0 + half) * HID + j] = acc;
        lsum += acc;
        lsq += acc * acc;
    }
    atomicAdd(&sums[j], lsum);
    atomicAdd(&sumsq[j], lsq);
}

// ---------------- BN stats -> scale/shift ----------------
__global__ void bnstat_kernel(const float* __restrict__ sums, const float* __restrict__ sumsq,
                              const float* __restrict__ gamma, const float* __restrict__ beta,
                              float* __restrict__ scale, float* __restrict__ shift) {
    int c = threadIdx.x;
    if (c < HID) {
        float inv_n = 1.0f / (float)NN;
        float mu = sums[c] * inv_n;
        float var = sumsq[c] * inv_n - mu * mu;
        float s = gamma[c] * rsqrtf(var + 1e-5f);
        scale[c] = s;
        shift[c] = beta[c] - mu * s;
    }
}

// ---------------- conv2 pre: h = relu(BN(hpre)); p = h@W2l -> hpre[n][64..); self -> out ----
__global__ __launch_bounds__(256) void conv2pre_kernel(
    float* __restrict__ hpre, const float* __restrict__ scale, const float* __restrict__ shift,
    const float* __restrict__ W2l, const float* __restrict__ b2, const float* __restrict__ W2r,
    float* __restrict__ outp, int npairs)
{
    __shared__ float hv[2][HID];
    int tid = threadIdx.x;
    int j = tid & 127;
    int half = tid >> 7;
    int jj = j & 63;
    const float* W = (j < 64) ? W2l : W2r;
    float w[HID];
#pragma unroll
    for (int k = 0; k < HID; k++) w[k] = W[k * OUTD + jj];
    float bj = (j >= 64) ? b2[jj] : 0.f;
    float sc = scale[j], sh = shift[j];
    for (int pr = blockIdx.x; pr < npairs; pr += gridDim.x) {
        int n0 = pr * 2;
        __syncthreads();
        {
            float v = hpre[(size_t)(n0 + half) * HID + j];
            v = v * sc + sh;
            hv[half][j] = (v > 0.f) ? v : 0.f;
        }
        __syncthreads();
        float acc = bj;
#pragma unroll
        for (int k = 0; k < HID; k++) acc += hv[half][k] * w[k];
        int n = n0 + half;
        if (j < 64) hpre[(size_t)n * HID + 64 + j] = acc;   // p (row already staged)
        else        outp[(size_t)n * 64 + jj] = acc;        // self term
    }
}

extern "C" void kernel_launch(void* const* d_in, const int* in_sizes, int n_in,
                              void* d_out, int out_size, void* d_ws, size_t ws_size,
                              hipStream_t stream) {
    const float* x     = (const float*)d_in[0];
    const int*   ei    = (const int*)d_in[1];
    const float* W1l   = (const float*)d_in[2];
    const float* b1    = (const float*)d_in[3];
    const float* W1r   = (const float*)d_in[4];
    const float* gamma = (const float*)d_in[5];
    const float* beta  = (const float*)d_in[6];
    const float* W2l   = (const float*)d_in[7];
    const float* b2    = (const float*)d_in[8];
    const float* W2r   = (const float*)d_in[9];
    float* out = (float*)d_out;

    // workspace layout (total ~29.2 MB)
    int*   cnt   = (int*)d_ws;                 // NN (reused as scatter cursor)
    int*   startp= cnt + NN;                   // NN (excl scan -> start, in place)
    int*   bsum  = cnt + 2 * NN;               // 256
    int*   boff  = bsum + 256;                 // 256
    int*   perm  = boff + 256;                 // NE
    float* hpre  = (float*)(perm + NE);        // NN*128; col [64..128) doubles as agg / p
    float* sums  = hpre + (size_t)NN * HID;    // 128
    float* sumsq = sums + 128;                 // 128
    float* scale = sums + 256;                 // 128
    float* shift = sums + 384;                 // 128

    const int* srcp = ei;
    const int* dstp = ei + NE;

    hipMemsetAsync(cnt, 0, sizeof(int) * NN, stream);
    hipMemsetAsync(sums, 0, sizeof(float) * 256, stream);

    const int EB = (NE + 255) / 256;           // 3125
    const int SB = (NN + 255) / 256;           // 196
    const int GB = (NN * 64 + 255) / 256;      // 12500 (one wave per node)

    hist_kernel<<<EB, 256, 0, stream>>>(dstp, cnt);
    scan1_kernel<<<SB, 256, 0, stream>>>(cnt, startp, bsum);
    scan2_kernel<<<1, 256, 0, stream>>>(bsum, boff, SB);
    scan3_kernel<<<SB, 256, 0, stream>>>(startp, boff, cnt);   // cnt becomes cursor
    scatter_kernel<<<EB, 256, 0, stream>>>(srcp, dstp, cnt, perm);

    // agg1: x (stride 16 f4, off 0) -> hpre cols [64..) (stride 32 f4, off 16)
    agg_gather_kernel<false><<<GB, 256, 0, stream>>>(
        (const float4*)x, 16, 0, startp, perm, (float4*)hpre, 32, 16);
    conv1_kernel<<<512, 256, 0, stream>>>(x, W1l, b1, W1r, hpre, sums, sumsq, NN / 2);
    bnstat_kernel<<<1, 128, 0, stream>>>(sums, sumsq, gamma, beta, scale, shift);
    conv2pre_kernel<<<512, 256, 0, stream>>>(hpre, scale, shift, W2l, b2, W2r, out, NN / 2);
    // agg2: p = hpre cols [64..) (stride 32, off 16) -> out (stride 16, off 0), accumulate
    agg_gather_kernel<true><<<GB, 256, 0, stream>>>(
        (const float4*)hpre, 32, 16, startp, perm, (float4*)out, 16, 0);
}